// Round 5
// baseline (777.027 us; speedup 1.0000x reference)
//
#include <hip/hip_runtime.h>
#include <hip/hip_fp16.h>
#include <hip/hip_cooperative_groups.h>
#include <math.h>

namespace cg = cooperative_groups;

#define IN 8000
#define OC 10
#define NSTAGE 500            // 500 stages x 16 i
#define VACC_F (64 * OC * 16) // 10240 floats

typedef __fp16 h2 __attribute__((ext_vector_type(2)));

__device__ __forceinline__ h2 asb(unsigned int v) { return __builtin_bit_cast(h2, v); }

__device__ __forceinline__ float dot2(h2 a, h2 b, float c) {
#if __has_builtin(__builtin_amdgcn_fdot2)
    return __builtin_amdgcn_fdot2(a, b, c, false);
#else
    return fmaf((float)a[0], (float)b[0], fmaf((float)a[1], (float)b[1], c));
#endif
}

__device__ __forceinline__ unsigned int pk_rn(float a, float b) {
    return __builtin_bit_cast(unsigned int, __float22half2_rn(make_float2(a, b)));
}

// sum over the t4 quad (lanes xor1, xor2) on the VALU via DPP quad_perm
// (avoids ds_swizzle on the LDS pipe, which is the bottleneck pipe here)
__device__ __forceinline__ float quad_sum(float v) {
    int a = __builtin_bit_cast(int, v);
    int s1 = __builtin_amdgcn_update_dpp(0, a, 0xB1, 0xF, 0xF, true);  // quad_perm [1,0,3,2]
    float v1 = v + __builtin_bit_cast(float, s1);
    int a2 = __builtin_bit_cast(int, v1);
    int s2 = __builtin_amdgcn_update_dpp(0, a2, 0x4E, 0xF, 0xF, true); // quad_perm [2,3,0,1]
    return v1 + __builtin_bit_cast(float, s2);
}

// One cooperative kernel runs all 3 routing passes. grid = min(500, 2*256)
// blocks x 1024 thr (16 waves = 4 bh x 4 ih). Lane = (bl:3 | oh:1 | t4:2).
// Thread owns b in {bh*16+bl, +8}, o in [5*oh,5*oh+5), d in [4*t4,4*t4+4).
// Block stages its 16-i W tile to LDS as f16 ONCE (reused across passes);
// x re-staged per pass (its LDS area doubles as the reduce buffer).
// Pass0 uses vac=0 -> softmax yields exactly c=0.1. Cross-block partials:
// fp32 atomicAdd into 8-way-split accumulators (one set per pass, zeroed at
// kernel start). Squash phase is grid-cooperative; grid.sync() between.
__global__ __launch_bounds__(1024, 8) void caps_mono(
    const float* __restrict__ W, const float* __restrict__ x,
    float* __restrict__ out, float* __restrict__ ws, int grid)
{
    __shared__ __align__(16) unsigned short Wl[16 * OC * 136];  // 43520 B, persists all passes
    __shared__ __align__(16) unsigned short xl[16 * 520];       // 16640 B; front 10240 B = red2
    float* red2 = (float*)xl;                                   // 2560 floats (+ sq at 2048)

    const int t    = threadIdx.x;
    const int w    = t >> 6;
    const int bh   = w >> 2;
    const int ih   = w & 3;
    const int lane = t & 63;
    const int bl   = lane >> 3;
    const int oh   = (lane >> 2) & 1;
    const int t4   = lane & 3;
    const int b0   = bh * 16 + bl;     // second batch: b0 + 8
    const int bid  = blockIdx.x;

    float* Vacc = ws;                  // 10240 f
    float* bufs = ws + VACC_F;         // 3 sets x 8 bufs x 10240 f

    cg::grid_group gg = cg::this_grid();

    // zero Vacc + all accumulator sets (ws is poisoned each launch)
    for (int idx = bid * 1024 + t; idx < VACC_F + 3 * 8 * VACC_F; idx += grid * 1024)
        ws[idx] = 0.f;
    gg.sync();

    bool wLoaded = false;

    for (int pass = 0; pass < 3; ++pass) {
        // load vac (pass>0); pass0: zeros -> softmax gives c = 1/10 exactly
        h2 vac[2][5][2];
#pragma unroll
        for (int j = 0; j < 2; ++j)
#pragma unroll
            for (int jo = 0; jo < 5; ++jo) {
                vac[j][jo][0] = asb(0u); vac[j][jo][1] = asb(0u);
            }
        if (pass > 0) {
#pragma unroll
            for (int j = 0; j < 2; ++j) {
                const float* vp = Vacc + (size_t)(b0 + j * 8) * (OC * 16) + (oh * 5) * 16 + t4 * 4;
#pragma unroll
                for (int jo = 0; jo < 5; ++jo) {
                    float4 v4 = *(const float4*)(vp + jo * 16);
                    vac[j][jo][0] = asb(pk_rn(v4.x, v4.y));
                    vac[j][jo][1] = asb(pk_rn(v4.z, v4.w));
                }
            }
        }

        float acc[2][5][4];
#pragma unroll
        for (int j = 0; j < 2; ++j)
#pragma unroll
            for (int jo = 0; jo < 5; ++jo)
#pragma unroll
                for (int k = 0; k < 4; ++k) acc[j][jo][k] = 0.f;

        for (int st = bid; st < NSTAGE; st += grid) {
            const int is = st * 16;
            __syncthreads();
            // stage W (f16, swizzle-padded rows of 136 halfs) — once if single-stage
            if (!(wLoaded && bid + grid >= NSTAGE)) {
                for (int j = t; j < 16 * 320; j += 1024) {
                    int iw = j / 320;
                    int r  = j - iw * 320;
                    int o  = r >> 5;
                    int f  = r & 31;
                    float4 w4 = *(const float4*)(W + (size_t)o * (IN * 128) +
                                                 (size_t)(is + iw) * 128 + f * 4);
                    *(uint2*)&Wl[iw * 1360 + o * 136 + f * 4] =
                        make_uint2(pk_rn(w4.x, w4.y), pk_rn(w4.z, w4.w));
                }
            }
            // stage x (f16) — every pass (its area doubles as red2)
            for (int j = t; j < 16 * 128; j += 1024) {
                int bb = j >> 5;
                int r  = j & 31;
                int iw = r >> 1;
                int hh = r & 1;
                float4 x4 = *(const float4*)(x + (size_t)bb * (IN * 8) +
                                             (size_t)(is + iw) * 8 + hh * 4);
                *(uint2*)&xl[iw * 520 + bb * 8 + hh * 4] =
                    make_uint2(pk_rn(x4.x, x4.y), pk_rn(x4.z, x4.w));
            }
            __syncthreads();

#pragma unroll 1
            for (int u = 0; u < 4; ++u) {
                const int il = ih * 4 + u;
                const unsigned short* wp = &Wl[il * 1360 + (oh * 5) * 136 + t4 * 32];
                const unsigned short* xp = &xl[il * 520];

                uint4 xq0 = *(const uint4*)(xp + b0 * 8);
                uint4 xq1 = *(const uint4*)(xp + (b0 + 8) * 8);
                h2 xv[2][4];
                xv[0][0] = asb(xq0.x); xv[0][1] = asb(xq0.y); xv[0][2] = asb(xq0.z); xv[0][3] = asb(xq0.w);
                xv[1][0] = asb(xq1.x); xv[1][1] = asb(xq1.y); xv[1][2] = asb(xq1.z); xv[1][3] = asb(xq1.w);

                float lg[2][5];
                h2 uh[2][5][2];
#pragma unroll
                for (int jo = 0; jo < 5; ++jo) {
                    const unsigned short* wo = wp + jo * 136;
                    uint4 q0 = *(const uint4*)(wo);
                    uint4 q1 = *(const uint4*)(wo + 8);
                    uint4 q2 = *(const uint4*)(wo + 16);
                    uint4 q3 = *(const uint4*)(wo + 24);
#pragma unroll
                    for (int j = 0; j < 2; ++j) {
                        float u0 = dot2(asb(q0.x), xv[j][0], 0.f);
                        u0 = dot2(asb(q0.y), xv[j][1], u0);
                        u0 = dot2(asb(q0.z), xv[j][2], u0);
                        u0 = dot2(asb(q0.w), xv[j][3], u0);
                        float u1 = dot2(asb(q1.x), xv[j][0], 0.f);
                        u1 = dot2(asb(q1.y), xv[j][1], u1);
                        u1 = dot2(asb(q1.z), xv[j][2], u1);
                        u1 = dot2(asb(q1.w), xv[j][3], u1);
                        float u2 = dot2(asb(q2.x), xv[j][0], 0.f);
                        u2 = dot2(asb(q2.y), xv[j][1], u2);
                        u2 = dot2(asb(q2.z), xv[j][2], u2);
                        u2 = dot2(asb(q2.w), xv[j][3], u2);
                        float u3 = dot2(asb(q3.x), xv[j][0], 0.f);
                        u3 = dot2(asb(q3.y), xv[j][1], u3);
                        u3 = dot2(asb(q3.z), xv[j][2], u3);
                        u3 = dot2(asb(q3.w), xv[j][3], u3);
                        h2 p0 = __builtin_amdgcn_cvt_pkrtz(u0, u1);
                        h2 p1 = __builtin_amdgcn_cvt_pkrtz(u2, u3);
                        uh[j][jo][0] = p0;
                        uh[j][jo][1] = p1;
                        lg[j][jo] = dot2(p0, vac[j][jo][0], dot2(p1, vac[j][jo][1], 0.f));
                    }
                }

#pragma unroll
                for (int j = 0; j < 2; ++j) {
#pragma unroll
                    for (int jo = 0; jo < 5; ++jo) lg[j][jo] = quad_sum(lg[j][jo]);
                    float lo[5];
#pragma unroll
                    for (int jo = 0; jo < 5; ++jo) lo[jo] = __shfl_xor(lg[j][jo], 4);
                    float mx = lg[j][0];
#pragma unroll
                    for (int jo = 1; jo < 5; ++jo) mx = fmaxf(mx, lg[j][jo]);
#pragma unroll
                    for (int jo = 0; jo < 5; ++jo) mx = fmaxf(mx, lo[jo]);
                    float c[5];
                    float se = 0.f;
#pragma unroll
                    for (int jo = 0; jo < 5; ++jo) { c[jo] = __expf(lg[j][jo] - mx); se += c[jo]; }
#pragma unroll
                    for (int jo = 0; jo < 5; ++jo) se += __expf(lo[jo] - mx);
                    float rs = 1.f / se;
#pragma unroll
                    for (int jo = 0; jo < 5; ++jo) {
                        float cj = c[jo] * rs;
                        acc[j][jo][0] += cj * (float)uh[j][jo][0][0];
                        acc[j][jo][1] += cj * (float)uh[j][jo][0][1];
                        acc[j][jo][2] += cj * (float)uh[j][jo][1][0];
                        acc[j][jo][3] += cj * (float)uh[j][jo][1][1];
                    }
                }
            }
        }
        wLoaded = true;

        // block reduce (per bh-group, 16-b red2 tile) + atomicAdd to this pass's buf
        float* abuf = bufs + ((size_t)pass * 8 + (bid & 7)) * VACC_F;
#pragma unroll 1
        for (int bh2 = 0; bh2 < 4; ++bh2) {
#pragma unroll 1
            for (int ih2 = 0; ih2 < 4; ++ih2) {
                __syncthreads();
                if (bh == bh2 && ih == ih2) {
#pragma unroll
                    for (int j = 0; j < 2; ++j)
#pragma unroll
                        for (int jo = 0; jo < 5; ++jo)
#pragma unroll
                            for (int k = 0; k < 4; ++k) {
                                int idx = (bl + j * 8) * 160 + (oh * 5 + jo) * 16 + t4 * 4 + k;
                                if (ih2 == 0) red2[idx] = acc[j][jo][k];
                                else          red2[idx] += acc[j][jo][k];
                            }
                }
            }
            __syncthreads();
            for (int idx = t; idx < 2560; idx += 1024)
                atomicAdd(abuf + bh2 * 2560 + idx, red2[idx]);
        }
        gg.sync();

        // squash phase: pair p=(b*10+o) -> v; write Vacc (pass0 =, pass1 +=) or out
        for (int p0 = bid; p0 < 640; p0 += grid) {
            float v = 0.f;
            const int d = t & 15;
            if (t < 128)
                v = bufs[((size_t)pass * 8 + (t >> 4)) * VACC_F + p0 * 16 + d];
            v += __shfl_xor(v, 16);
            v += __shfl_xor(v, 32);
            __syncthreads();
            if (t < 16)              red2[2048 + t] = v;          // bufs 0-3
            if (t >= 64 && t < 80)   red2[2064 + (t & 15)] = v;   // bufs 4-7
            __syncthreads();
            if (t < 16) {
                float sv = red2[2048 + t] + red2[2064 + t];
                float n2 = sv * sv;
#pragma unroll
                for (int m = 1; m < 16; m <<= 1) n2 += __shfl_xor(n2, m);
                float norm = sqrtf(n2);
                float scl  = n2 / (1.f + n2) / (norm + 1e-8f);
                float vv   = scl * sv;
                if (pass == 2)      out[p0 * 16 + t] = vv;
                else if (pass == 0) Vacc[p0 * 16 + t] = vv;
                else                Vacc[p0 * 16 + t] += vv;
            }
            __syncthreads();
        }
        if (pass < 2) gg.sync();
    }
}

extern "C" void kernel_launch(void* const* d_in, const int* in_sizes, int n_in,
                              void* d_out, int out_size, void* d_ws, size_t ws_size,
                              hipStream_t stream) {
    const float* x = (const float*)d_in[0];   // (64, 8000, 8)
    const float* W = (const float*)d_in[1];   // (10, 8000, 16, 8)
    float* out = (float*)d_out;               // (64, 10, 16)
    float* wsf = (float*)d_ws;                // Vacc + 3x8 accumulator sets (~1 MB)

    int maxB = 0;
    (void)hipOccupancyMaxActiveBlocksPerMultiprocessor(&maxB, caps_mono, 1024, 0);
    int grid = (maxB > 0 ? maxB : 1) * 256;
    if (grid > NSTAGE) grid = NSTAGE;

    void* args[] = { (void*)&W, (void*)&x, (void*)&out, (void*)&wsf, (void*)&grid };
    hipLaunchCooperativeKernel((const void*)caps_mono, dim3(grid), dim3(1024),
                               args, 0, stream);
}

// Round 6
// 517.808 us; speedup vs baseline: 1.5006x; 1.5006x over previous
//
#include <hip/hip_runtime.h>
#include <hip/hip_fp16.h>
#include <hip/hip_cooperative_groups.h>
#include <math.h>

namespace cg = cooperative_groups;

#define IN 8000
#define OC 10
#define NSTAGE 500            // 500 stages x 16 i
#define VACC_F (64 * OC * 16) // 10240 floats

typedef __fp16 h2 __attribute__((ext_vector_type(2)));

__device__ __forceinline__ h2 asb(unsigned int v) { return __builtin_bit_cast(h2, v); }

__device__ __forceinline__ float dot2(h2 a, h2 b, float c) {
#if __has_builtin(__builtin_amdgcn_fdot2)
    return __builtin_amdgcn_fdot2(a, b, c, false);
#else
    return fmaf((float)a[0], (float)b[0], fmaf((float)a[1], (float)b[1], c));
#endif
}

__device__ __forceinline__ unsigned int pk_rn(float a, float b) {
    return __builtin_bit_cast(unsigned int, __float22half2_rn(make_float2(a, b)));
}

// t4-quad sum (lanes xor1, xor2) on the VALU via DPP quad_perm
__device__ __forceinline__ float quad_sum(float v) {
    int a = __builtin_bit_cast(int, v);
    int s1 = __builtin_amdgcn_update_dpp(0, a, 0xB1, 0xF, 0xF, true);  // [1,0,3,2]
    float v1 = v + __builtin_bit_cast(float, s1);
    int a2 = __builtin_bit_cast(int, v1);
    int s2 = __builtin_amdgcn_update_dpp(0, a2, 0x4E, 0xF, 0xF, true); // [2,3,0,1]
    return v1 + __builtin_bit_cast(float, s2);
}

// Cooperative mono-kernel: all 3 routing passes in one dispatch.
// grid = min(500, maxB*256) blocks x 1024 thr (16 waves = 4 bh x 4 ih).
// Lane = (bl:3 | oh:1 | t4:2). Thread owns b in {bh*16+bl, +8},
// o in [5*oh,5*oh+5), d in [4*t4,4*t4+4).
// At grid=500 each block owns ONE 16-i stage: W and x are staged to LDS as
// f16 once in pass 0 and reused by passes 1-2 with no staging barriers.
// red2 has its own LDS (not aliased) to make that possible.
// Pass 0: c=0.1 folded into squash scale (no uh / softmax).
// Cross-block: fp32 atomicAdd into 8-way-split per-pass buffers (zeroed at
// start); squash is grid-cooperative.
// NOTE: no min-waves in launch_bounds — R5's (1024,8) forced VGPR=32 and
// ~1.9 GB of scratch spill. Natural allocation here is ~64 VGPR = 8 w/SIMD.
__global__ __launch_bounds__(1024) void caps_mono(
    const float* __restrict__ W, const float* __restrict__ x,
    float* __restrict__ out, float* __restrict__ ws, int grid)
{
    __shared__ __align__(16) unsigned short Wl[16 * OC * 136];  // 43520 B
    __shared__ __align__(16) unsigned short xl[16 * 520];       // 16640 B
    __shared__ __align__(16) float red2[2560];                  // 10240 B

    const int t    = threadIdx.x;
    const int w    = t >> 6;
    const int bh   = w >> 2;
    const int ih   = w & 3;
    const int lane = t & 63;
    const int bl   = lane >> 3;
    const int oh   = (lane >> 2) & 1;
    const int t4   = lane & 3;
    const int b0   = bh * 16 + bl;     // second batch: b0 + 8
    const int bid  = blockIdx.x;
    const bool oneStage = (bid + grid >= NSTAGE);

    float* Vacc = ws;                  // 10240 f (pass0 squash overwrites; never pre-read)
    float* bufs = ws + VACC_F;         // 3 sets x 8 bufs x 10240 f

    cg::grid_group gg = cg::this_grid();

    // zero the atomic accumulator sets (ws is poisoned each launch)
    for (int idx = bid * 1024 + t; idx < 3 * 8 * VACC_F; idx += grid * 1024)
        bufs[idx] = 0.f;
    gg.sync();

    bool wLoaded = false;

    for (int pass = 0; pass < 3; ++pass) {
        const bool p0 = (pass == 0);

        h2 vac[2][5][2];
        if (!p0) {
#pragma unroll
            for (int j = 0; j < 2; ++j) {
                const float* vp = Vacc + (size_t)(b0 + j * 8) * (OC * 16) + (oh * 5) * 16 + t4 * 4;
#pragma unroll
                for (int jo = 0; jo < 5; ++jo) {
                    float4 v4 = *(const float4*)(vp + jo * 16);
                    vac[j][jo][0] = asb(pk_rn(v4.x, v4.y));
                    vac[j][jo][1] = asb(pk_rn(v4.z, v4.w));
                }
            }
        }

        float acc[2][5][4];
#pragma unroll
        for (int j = 0; j < 2; ++j)
#pragma unroll
            for (int jo = 0; jo < 5; ++jo)
#pragma unroll
                for (int k = 0; k < 4; ++k) acc[j][jo][k] = 0.f;

        for (int st = bid; st < NSTAGE; st += grid) {
            const int is = st * 16;
            const bool doStage = !(wLoaded && oneStage);
            if (doStage) {
                __syncthreads();
                // stage W (f16, rows padded to 136 halfs)
                for (int j = t; j < 16 * 320; j += 1024) {
                    int iw = j / 320;
                    int r  = j - iw * 320;
                    int o  = r >> 5;
                    int f  = r & 31;
                    float4 w4 = *(const float4*)(W + (size_t)o * (IN * 128) +
                                                 (size_t)(is + iw) * 128 + f * 4);
                    *(uint2*)&Wl[iw * 1360 + o * 136 + f * 4] =
                        make_uint2(pk_rn(w4.x, w4.y), pk_rn(w4.z, w4.w));
                }
                // stage x (f16)
                for (int j = t; j < 16 * 128; j += 1024) {
                    int bb = j >> 5;
                    int r  = j & 31;
                    int iw = r >> 1;
                    int hh = r & 1;
                    float4 x4 = *(const float4*)(x + (size_t)bb * (IN * 8) +
                                                 (size_t)(is + iw) * 8 + hh * 4);
                    *(uint2*)&xl[iw * 520 + bb * 8 + hh * 4] =
                        make_uint2(pk_rn(x4.x, x4.y), pk_rn(x4.z, x4.w));
                }
                __syncthreads();
            }

#pragma unroll 1
            for (int u = 0; u < 4; ++u) {
                const int il = ih * 4 + u;
                const unsigned short* wp = &Wl[il * 1360 + (oh * 5) * 136 + t4 * 32];
                const unsigned short* xp = &xl[il * 520];

                uint4 xq0 = *(const uint4*)(xp + b0 * 8);
                uint4 xq1 = *(const uint4*)(xp + (b0 + 8) * 8);
                h2 xv[2][4];
                xv[0][0] = asb(xq0.x); xv[0][1] = asb(xq0.y); xv[0][2] = asb(xq0.z); xv[0][3] = asb(xq0.w);
                xv[1][0] = asb(xq1.x); xv[1][1] = asb(xq1.y); xv[1][2] = asb(xq1.z); xv[1][3] = asb(xq1.w);

                float lg[2][5];
                h2 uh[2][5][2];
#pragma unroll
                for (int jo = 0; jo < 5; ++jo) {
                    const unsigned short* wo = wp + jo * 136;
                    uint4 q0 = *(const uint4*)(wo);
                    uint4 q1 = *(const uint4*)(wo + 8);
                    uint4 q2 = *(const uint4*)(wo + 16);
                    uint4 q3 = *(const uint4*)(wo + 24);
#pragma unroll
                    for (int j = 0; j < 2; ++j) {
                        float u0 = dot2(asb(q0.x), xv[j][0], 0.f);
                        u0 = dot2(asb(q0.y), xv[j][1], u0);
                        u0 = dot2(asb(q0.z), xv[j][2], u0);
                        u0 = dot2(asb(q0.w), xv[j][3], u0);
                        float u1 = dot2(asb(q1.x), xv[j][0], 0.f);
                        u1 = dot2(asb(q1.y), xv[j][1], u1);
                        u1 = dot2(asb(q1.z), xv[j][2], u1);
                        u1 = dot2(asb(q1.w), xv[j][3], u1);
                        float u2 = dot2(asb(q2.x), xv[j][0], 0.f);
                        u2 = dot2(asb(q2.y), xv[j][1], u2);
                        u2 = dot2(asb(q2.z), xv[j][2], u2);
                        u2 = dot2(asb(q2.w), xv[j][3], u2);
                        float u3 = dot2(asb(q3.x), xv[j][0], 0.f);
                        u3 = dot2(asb(q3.y), xv[j][1], u3);
                        u3 = dot2(asb(q3.z), xv[j][2], u3);
                        u3 = dot2(asb(q3.w), xv[j][3], u3);
                        if (p0) {   // c=0.1 folded into squash scale
                            acc[j][jo][0] += u0;
                            acc[j][jo][1] += u1;
                            acc[j][jo][2] += u2;
                            acc[j][jo][3] += u3;
                        } else {
                            h2 pk0 = __builtin_amdgcn_cvt_pkrtz(u0, u1);
                            h2 pk1 = __builtin_amdgcn_cvt_pkrtz(u2, u3);
                            uh[j][jo][0] = pk0;
                            uh[j][jo][1] = pk1;
                            lg[j][jo] = dot2(pk0, vac[j][jo][0], dot2(pk1, vac[j][jo][1], 0.f));
                        }
                    }
                }

                if (!p0) {
#pragma unroll
                    for (int j = 0; j < 2; ++j) {
#pragma unroll
                        for (int jo = 0; jo < 5; ++jo) lg[j][jo] = quad_sum(lg[j][jo]);
                        float lo[5];
#pragma unroll
                        for (int jo = 0; jo < 5; ++jo) lo[jo] = __shfl_xor(lg[j][jo], 4);
                        float mx = lg[j][0];
#pragma unroll
                        for (int jo = 1; jo < 5; ++jo) mx = fmaxf(mx, lg[j][jo]);
#pragma unroll
                        for (int jo = 0; jo < 5; ++jo) mx = fmaxf(mx, lo[jo]);
                        float c[5];
                        float se = 0.f;
#pragma unroll
                        for (int jo = 0; jo < 5; ++jo) { c[jo] = __expf(lg[j][jo] - mx); se += c[jo]; }
#pragma unroll
                        for (int jo = 0; jo < 5; ++jo) se += __expf(lo[jo] - mx);
                        float rs = 1.f / se;
#pragma unroll
                        for (int jo = 0; jo < 5; ++jo) {
                            float cj = c[jo] * rs;
                            acc[j][jo][0] += cj * (float)uh[j][jo][0][0];
                            acc[j][jo][1] += cj * (float)uh[j][jo][0][1];
                            acc[j][jo][2] += cj * (float)uh[j][jo][1][0];
                            acc[j][jo][3] += cj * (float)uh[j][jo][1][1];
                        }
                    }
                }
            }
        }
        wLoaded = true;

        // block reduce via red2 + atomicAdd into this pass's 8-way-split buf
        float* abuf = bufs + ((size_t)pass * 8 + (bid & 7)) * VACC_F;
#pragma unroll 1
        for (int bh2 = 0; bh2 < 4; ++bh2) {
#pragma unroll 1
            for (int ih2 = 0; ih2 < 4; ++ih2) {
                __syncthreads();
                if (bh == bh2 && ih == ih2) {
#pragma unroll
                    for (int j = 0; j < 2; ++j)
#pragma unroll
                        for (int jo = 0; jo < 5; ++jo)
#pragma unroll
                            for (int k = 0; k < 4; ++k) {
                                int idx = (bl + j * 8) * 160 + (oh * 5 + jo) * 16 + t4 * 4 + k;
                                if (ih2 == 0) red2[idx] = acc[j][jo][k];
                                else          red2[idx] += acc[j][jo][k];
                            }
                }
            }
            __syncthreads();
            for (int idx = t; idx < 2560; idx += 1024)
                atomicAdd(abuf + bh2 * 2560 + idx, red2[idx]);
        }
        gg.sync();

        // squash: pair p = b*10+o; sum the 8 bufs, squash, write Vacc/out
        const float pscale = p0 ? 0.1f : 1.0f;
        for (int pp = bid; pp < 640; pp += grid) {
            float v = 0.f;
            const int d = t & 15;
            if (t < 128)
                v = bufs[((size_t)pass * 8 + (t >> 4)) * VACC_F + pp * 16 + d];
            v += __shfl_xor(v, 16);
            v += __shfl_xor(v, 32);
            __syncthreads();
            if (t < 16)             red2[2048 + t] = v;           // bufs 0-3
            if (t >= 64 && t < 80)  red2[2064 + (t & 15)] = v;    // bufs 4-7
            __syncthreads();
            if (t < 16) {
                float sv = (red2[2048 + t] + red2[2064 + t]) * pscale;
                float n2 = sv * sv;
#pragma unroll
                for (int m = 1; m < 16; m <<= 1) n2 += __shfl_xor(n2, m);
                float norm = sqrtf(n2);
                float scl  = n2 / (1.f + n2) / (norm + 1e-8f);
                float vv   = scl * sv;
                if (pass == 2)      out[pp * 16 + t] = vv;
                else if (pass == 0) Vacc[pp * 16 + t] = vv;
                else                Vacc[pp * 16 + t] += vv;
            }
            __syncthreads();
        }
        if (pass < 2) gg.sync();
    }
}

extern "C" void kernel_launch(void* const* d_in, const int* in_sizes, int n_in,
                              void* d_out, int out_size, void* d_ws, size_t ws_size,
                              hipStream_t stream) {
    const float* x = (const float*)d_in[0];   // (64, 8000, 8)
    const float* W = (const float*)d_in[1];   // (10, 8000, 16, 8)
    float* out = (float*)d_out;               // (64, 10, 16)
    float* wsf = (float*)d_ws;                // Vacc + 3x8 accumulator sets (~1 MB)

    int maxB = 0;
    (void)hipOccupancyMaxActiveBlocksPerMultiprocessor(&maxB, caps_mono, 1024, 0);
    int grid = (maxB > 0 ? maxB : 1) * 256;
    if (grid > NSTAGE) grid = NSTAGE;

    void* args[] = { (void*)&W, (void*)&x, (void*)&out, (void*)&wsf, (void*)&grid };
    hipLaunchCooperativeKernel((const void*)caps_mono, dim3(grid), dim3(1024),
                               args, 0, stream);
}

// Round 7
// 515.672 us; speedup vs baseline: 1.5068x; 1.0041x over previous
//
#include <hip/hip_runtime.h>
#include <hip/hip_fp16.h>
#include <hip/hip_cooperative_groups.h>
#include <math.h>

namespace cg = cooperative_groups;

#define IN 8000
#define OC 10
#define NSTAGE 500             // 500 stages x 16 i
#define VACC_F (64 * OC * 16)  // 10240 floats
#define PART_F (4 * 2560)      // per-block partial: [4 bh][2560] floats = 40 KB

typedef __fp16 h2 __attribute__((ext_vector_type(2)));

__device__ __forceinline__ h2 asb(unsigned int v) { return __builtin_bit_cast(h2, v); }

__device__ __forceinline__ float dot2(h2 a, h2 b, float c) {
#if __has_builtin(__builtin_amdgcn_fdot2)
    return __builtin_amdgcn_fdot2(a, b, c, false);
#else
    return fmaf((float)a[0], (float)b[0], fmaf((float)a[1], (float)b[1], c));
#endif
}

__device__ __forceinline__ unsigned int pk_rn(float a, float b) {
    return __builtin_bit_cast(unsigned int, __float22half2_rn(make_float2(a, b)));
}

// t4-quad sum (lanes xor1, xor2) on the VALU via DPP quad_perm
__device__ __forceinline__ float quad_sum(float v) {
    int a = __builtin_bit_cast(int, v);
    int s1 = __builtin_amdgcn_update_dpp(0, a, 0xB1, 0xF, 0xF, true);  // [1,0,3,2]
    float v1 = v + __builtin_bit_cast(float, s1);
    int a2 = __builtin_bit_cast(int, v1);
    int s2 = __builtin_amdgcn_update_dpp(0, a2, 0x4E, 0xF, 0xF, true); // [2,3,0,1]
    return v1 + __builtin_bit_cast(float, s2);
}

// Cooperative mono-kernel, all 3 routing passes in one dispatch.
// grid = min(500, ws slots, occupancyAPI*256) blocks x 1024 thr
// (16 waves = 4 bh x 4 ih). Lane = (bl:3 | oh:1 | t4:2). Thread owns
// b in {bh*16+bl, +8}, o in [5*oh,5*oh+5), d in [4*t4,4*t4+4).
// LDS = 60160 B (<= R5's proven-coresident 60416): red2 aliases xl, so W
// stays LDS-resident across passes for single-stage blocks; x re-staged
// per pass (16 MB HBM, cheap). NO global atomics: block accumulates its
// stages in registers, writes ONE plain 40 KB partial; squash phase
// tree-reduces over grid partials cooperatively. Block-reduce uses a
// transposed red2 layout (k*64+lane -> stride-1, conflict-free) with
// ih0-write + ih1..3 LDS-atomicAdd (ds_add_f32), flushed in canonical
// order so squash reads are coalesced.
__global__ __launch_bounds__(1024) void caps_mono(
    const float* __restrict__ W, const float* __restrict__ x,
    float* __restrict__ out, float* __restrict__ ws, int grid)
{
    __shared__ __align__(16) unsigned short Wl[16 * OC * 136];  // 43520 B
    __shared__ __align__(16) unsigned short xl[16 * 520];       // 16640 B
    float* red2 = (float*)xl;                                   // 2560 f (aliased)

    const int t    = threadIdx.x;
    const int w    = t >> 6;
    const int bh   = w >> 2;
    const int ih   = w & 3;
    const int lane = t & 63;
    const int bl   = lane >> 3;
    const int oh   = (lane >> 2) & 1;
    const int t4   = lane & 3;
    const int b0   = bh * 16 + bl;     // second batch: b0 + 8
    const int bid  = blockIdx.x;
    const bool oneStage = (bid + grid >= NSTAGE);

    float* Vacc = ws;                  // 10240 f (pass0 writes before any read)
    float* part = ws + VACC_F;         // grid x PART_F floats

    cg::grid_group gg = cg::this_grid();
    bool wLoaded = false;

    for (int pass = 0; pass < 3; ++pass) {
        const bool p0 = (pass == 0);

        h2 vac[2][5][2];
        if (!p0) {
#pragma unroll
            for (int j = 0; j < 2; ++j) {
                const float* vp = Vacc + (size_t)(b0 + j * 8) * (OC * 16) + (oh * 5) * 16 + t4 * 4;
#pragma unroll
                for (int jo = 0; jo < 5; ++jo) {
                    float4 v4 = *(const float4*)(vp + jo * 16);
                    vac[j][jo][0] = asb(pk_rn(v4.x, v4.y));
                    vac[j][jo][1] = asb(pk_rn(v4.z, v4.w));
                }
            }
        }

        float acc[2][5][4];
#pragma unroll
        for (int j = 0; j < 2; ++j)
#pragma unroll
            for (int jo = 0; jo < 5; ++jo)
#pragma unroll
                for (int k = 0; k < 4; ++k) acc[j][jo][k] = 0.f;

        for (int st = bid; st < NSTAGE; st += grid) {
            const int is = st * 16;
            __syncthreads();
            // stage W only if not LDS-resident from pass 0
            if (!(wLoaded && oneStage)) {
                for (int j = t; j < 16 * 320; j += 1024) {
                    int iw = j / 320;
                    int r  = j - iw * 320;
                    int o  = r >> 5;
                    int f  = r & 31;
                    float4 w4 = *(const float4*)(W + (size_t)o * (IN * 128) +
                                                 (size_t)(is + iw) * 128 + f * 4);
                    *(uint2*)&Wl[iw * 1360 + o * 136 + f * 4] =
                        make_uint2(pk_rn(w4.x, w4.y), pk_rn(w4.z, w4.w));
                }
            }
            // stage x every pass (its LDS is clobbered by red2 each pass)
            for (int j = t; j < 16 * 128; j += 1024) {
                int bb = j >> 5;
                int r  = j & 31;
                int iw = r >> 1;
                int hh = r & 1;
                float4 x4 = *(const float4*)(x + (size_t)bb * (IN * 8) +
                                             (size_t)(is + iw) * 8 + hh * 4);
                *(uint2*)&xl[iw * 520 + bb * 8 + hh * 4] =
                    make_uint2(pk_rn(x4.x, x4.y), pk_rn(x4.z, x4.w));
            }
            __syncthreads();

#pragma unroll 1
            for (int u = 0; u < 4; ++u) {
                const int il = ih * 4 + u;
                const unsigned short* wp = &Wl[il * 1360 + (oh * 5) * 136 + t4 * 32];
                const unsigned short* xp = &xl[il * 520];

                uint4 xq0 = *(const uint4*)(xp + b0 * 8);
                uint4 xq1 = *(const uint4*)(xp + (b0 + 8) * 8);
                h2 xv[2][4];
                xv[0][0] = asb(xq0.x); xv[0][1] = asb(xq0.y); xv[0][2] = asb(xq0.z); xv[0][3] = asb(xq0.w);
                xv[1][0] = asb(xq1.x); xv[1][1] = asb(xq1.y); xv[1][2] = asb(xq1.z); xv[1][3] = asb(xq1.w);

                float lg[2][5];
                h2 uh[2][5][2];
#pragma unroll
                for (int jo = 0; jo < 5; ++jo) {
                    const unsigned short* wo = wp + jo * 136;
                    uint4 q0 = *(const uint4*)(wo);
                    uint4 q1 = *(const uint4*)(wo + 8);
                    uint4 q2 = *(const uint4*)(wo + 16);
                    uint4 q3 = *(const uint4*)(wo + 24);
#pragma unroll
                    for (int j = 0; j < 2; ++j) {
                        float u0 = dot2(asb(q0.x), xv[j][0], 0.f);
                        u0 = dot2(asb(q0.y), xv[j][1], u0);
                        u0 = dot2(asb(q0.z), xv[j][2], u0);
                        u0 = dot2(asb(q0.w), xv[j][3], u0);
                        float u1 = dot2(asb(q1.x), xv[j][0], 0.f);
                        u1 = dot2(asb(q1.y), xv[j][1], u1);
                        u1 = dot2(asb(q1.z), xv[j][2], u1);
                        u1 = dot2(asb(q1.w), xv[j][3], u1);
                        float u2 = dot2(asb(q2.x), xv[j][0], 0.f);
                        u2 = dot2(asb(q2.y), xv[j][1], u2);
                        u2 = dot2(asb(q2.z), xv[j][2], u2);
                        u2 = dot2(asb(q2.w), xv[j][3], u2);
                        float u3 = dot2(asb(q3.x), xv[j][0], 0.f);
                        u3 = dot2(asb(q3.y), xv[j][1], u3);
                        u3 = dot2(asb(q3.z), xv[j][2], u3);
                        u3 = dot2(asb(q3.w), xv[j][3], u3);
                        if (p0) {   // c=0.1 folded into squash scale
                            acc[j][jo][0] += u0;
                            acc[j][jo][1] += u1;
                            acc[j][jo][2] += u2;
                            acc[j][jo][3] += u3;
                        } else {
                            h2 pk0 = __builtin_amdgcn_cvt_pkrtz(u0, u1);
                            h2 pk1 = __builtin_amdgcn_cvt_pkrtz(u2, u3);
                            uh[j][jo][0] = pk0;
                            uh[j][jo][1] = pk1;
                            lg[j][jo] = dot2(pk0, vac[j][jo][0], dot2(pk1, vac[j][jo][1], 0.f));
                        }
                    }
                }

                if (!p0) {
#pragma unroll
                    for (int j = 0; j < 2; ++j) {
#pragma unroll
                        for (int jo = 0; jo < 5; ++jo) lg[j][jo] = quad_sum(lg[j][jo]);
                        float lo[5];
#pragma unroll
                        for (int jo = 0; jo < 5; ++jo) lo[jo] = __shfl_xor(lg[j][jo], 4);
                        float mx = lg[j][0];
#pragma unroll
                        for (int jo = 1; jo < 5; ++jo) mx = fmaxf(mx, lg[j][jo]);
#pragma unroll
                        for (int jo = 0; jo < 5; ++jo) mx = fmaxf(mx, lo[jo]);
                        float c[5];
                        float se = 0.f;
#pragma unroll
                        for (int jo = 0; jo < 5; ++jo) { c[jo] = __expf(lg[j][jo] - mx); se += c[jo]; }
#pragma unroll
                        for (int jo = 0; jo < 5; ++jo) se += __expf(lo[jo] - mx);
                        float rs = 1.f / se;
#pragma unroll
                        for (int jo = 0; jo < 5; ++jo) {
                            float cj = c[jo] * rs;
                            acc[j][jo][0] += cj * (float)uh[j][jo][0][0];
                            acc[j][jo][1] += cj * (float)uh[j][jo][0][1];
                            acc[j][jo][2] += cj * (float)uh[j][jo][1][0];
                            acc[j][jo][3] += cj * (float)uh[j][jo][1][1];
                        }
                    }
                }
            }
        }
        wLoaded = true;

        // block reduce: transposed red2 (idx = (j*5+jo)*256 + k*64 + lane,
        // stride-1 per instruction -> conflict-free), ih0 writes, ih1-3
        // ds_add_f32; flush in canonical (b,o,d) order, plain stores.
#pragma unroll 1
        for (int bh2 = 0; bh2 < 4; ++bh2) {
            __syncthreads();
            if (bh == bh2 && ih == 0) {
#pragma unroll
                for (int j = 0; j < 2; ++j)
#pragma unroll
                    for (int jo = 0; jo < 5; ++jo)
#pragma unroll
                        for (int k = 0; k < 4; ++k)
                            red2[(j * 5 + jo) * 256 + k * 64 + lane] = acc[j][jo][k];
            }
            __syncthreads();
            if (bh == bh2 && ih != 0) {
#pragma unroll
                for (int j = 0; j < 2; ++j)
#pragma unroll
                    for (int jo = 0; jo < 5; ++jo)
#pragma unroll
                        for (int k = 0; k < 4; ++k)
                            atomicAdd(&red2[(j * 5 + jo) * 256 + k * 64 + lane], acc[j][jo][k]);
            }
            __syncthreads();
            // canonical element q = (j*5+jo)*256 + lane'*4 + k
            float* dst = part + (size_t)bid * PART_F + bh2 * 2560;
            for (int q = t; q < 2560; q += 1024)
                dst[q] = red2[(q >> 8) * 256 + (q & 3) * 64 + ((q >> 2) & 63)];
        }
        gg.sync();

        // cooperative squash: pair pp = b*10+o over grid blocks
        const float pscale = p0 ? 0.1f : 1.0f;
        for (int pp = bid; pp < 640; pp += grid) {
            const int bb  = pp / 10;
            const int oo  = pp - bb * 10;
            const int bh_ = bb >> 4;
            const int low = bb & 15;
            const int jj  = low >> 3;
            const int bll = low & 7;
            const int ohh = (oo >= 5) ? 1 : 0;
            const int joo = oo - ohh * 5;
            const int base = (jj * 5 + joo) * 256 + (bll * 8 + ohh * 4) * 4;
            const int d = t & 15;
            const int s = t >> 4;
            float v = 0.f;
            for (int c = s; c < grid; c += 64)
                v += part[(size_t)c * PART_F + bh_ * 2560 + base + d];
            v += __shfl_xor(v, 16);
            v += __shfl_xor(v, 32);
            __syncthreads();
            if (lane < 16) red2[w * 16 + lane] = v;
            __syncthreads();
            if (t < 16) {
                float sv = 0.f;
#pragma unroll
                for (int w2 = 0; w2 < 16; ++w2) sv += red2[w2 * 16 + t];
                sv *= pscale;
                float n2 = sv * sv;
#pragma unroll
                for (int m = 1; m < 16; m <<= 1) n2 += __shfl_xor(n2, m);
                float norm = sqrtf(n2);
                float scl  = n2 / (1.f + n2) / (norm + 1e-8f);
                float vv   = scl * sv;
                if (pass == 2)      out[pp * 16 + t] = vv;
                else if (pass == 0) Vacc[pp * 16 + t] = vv;
                else                Vacc[pp * 16 + t] += vv;
            }
            __syncthreads();
        }
        if (pass < 2) gg.sync();
    }
}

extern "C" void kernel_launch(void* const* d_in, const int* in_sizes, int n_in,
                              void* d_out, int out_size, void* d_ws, size_t ws_size,
                              hipStream_t stream) {
    const float* x = (const float*)d_in[0];   // (64, 8000, 8)
    const float* W = (const float*)d_in[1];   // (10, 8000, 16, 8)
    float* out = (float*)d_out;               // (64, 10, 16)
    float* wsf = (float*)d_ws;                // Vacc + grid x 40 KB partials

    // grid: bounded by ws slots, stage count, and co-residency (API; R5
    // proved 500 blocks co-resident at LDS 60416 — we're at 60160).
    size_t wsf_words = ws_size / 4;
    size_t avail = (wsf_words > VACC_F) ? wsf_words - VACC_F : 0;
    long slots = (long)(avail / PART_F);
    int grid = (int)((slots < NSTAGE) ? slots : NSTAGE);
    int maxB = 0;
    if (hipOccupancyMaxActiveBlocksPerMultiprocessor(&maxB, caps_mono, 1024, 0)
        != hipSuccess || maxB < 1) maxB = 1;
    if (grid > maxB * 256) grid = maxB * 256;
    if (grid < 1) grid = 1;

    void* args[] = { (void*)&W, (void*)&x, (void*)&out, (void*)&wsf, (void*)&grid };
    hipLaunchCooperativeKernel((const void*)caps_mono, dim3(grid), dim3(1024),
                               args, 0, stream);
}

// Round 8
// 241.859 us; speedup vs baseline: 3.2127x; 2.1321x over previous
//
#include <hip/hip_runtime.h>
#include <hip/hip_fp16.h>
#include <math.h>

#define IN 8000
#define OC 10
#define NSTAGE 500              // 500 stages x 16 i
#define VACC_F (64 * OC * 16)   // 10240 floats
#define PART_H (64 * OC * 16)   // 10240 halfs per block partial (20 KB)

typedef __fp16 h2 __attribute__((ext_vector_type(2)));

__device__ __forceinline__ h2 asb(unsigned int v) { return __builtin_bit_cast(h2, v); }

__device__ __forceinline__ float dot2(h2 a, h2 b, float c) {
#if __has_builtin(__builtin_amdgcn_fdot2)
    return __builtin_amdgcn_fdot2(a, b, c, false);
#else
    return fmaf((float)a[0], (float)b[0], fmaf((float)a[1], (float)b[1], c));
#endif
}

__device__ __forceinline__ unsigned int pk_rn(float a, float b) {
    return __builtin_bit_cast(unsigned int, __float22half2_rn(make_float2(a, b)));
}

// t4-quad sum (lanes xor1, xor2) on the VALU via DPP quad_perm
__device__ __forceinline__ float quad_sum(float v) {
    int a = __builtin_bit_cast(int, v);
    int s1 = __builtin_amdgcn_update_dpp(0, a, 0xB1, 0xF, 0xF, true);  // [1,0,3,2]
    float v1 = v + __builtin_bit_cast(float, s1);
    int a2 = __builtin_bit_cast(int, v1);
    int s2 = __builtin_amdgcn_update_dpp(0, a2, 0x4E, 0xF, 0xF, true); // [2,3,0,1]
    return v1 + __builtin_bit_cast(float, s2);
}

// Kernel A (R4 structure, proven 50 us/pass at 250 blocks): grid = up to 500
// blocks x 1024 thr (16 waves = 4 bh x 4 ih); block handles stages
// st = bid, bid+grid, ... (exactly ONE 16-i stage at grid=500 -> 2 blocks/CU,
// overlapping barrier domains). Lane = (bl:3 | oh:1 | t4:2). Thread owns
// b in {bh*16+bl, +8}, o in [5*oh,5*oh+5), d in [4*t4,4*t4+4).
// W/x staged per stage to LDS as f16; inner: 22 ds_read_b128 + 160 dot2 per
// lane-i. Partial flushed as f16 (20 KB) so ~10 MB ws holds 500 slots.
template<int UNIFORM>
__global__ __launch_bounds__(1024) void caps_pass(
    const float* __restrict__ W, const float* __restrict__ x,
    const float* __restrict__ Vacc, __fp16* __restrict__ part)
{
    __shared__ __align__(16) unsigned short Wl[16 * OC * 136];  // 43520 B
    __shared__ __align__(16) unsigned short xl[16 * 520];       // 16640 B
    float* red = (float*)Wl;                                    // 10240 f alias

    const int t    = threadIdx.x;
    const int w    = t >> 6;
    const int bh   = w >> 2;
    const int ih   = w & 3;
    const int lane = t & 63;
    const int bl   = lane >> 3;
    const int oh   = (lane >> 2) & 1;
    const int t4   = lane & 3;
    const int b0   = bh * 16 + bl;     // second batch: b0 + 8
    const int bid  = blockIdx.x;
    const int grid = gridDim.x;

    h2 vac[2][5][2];
    if (!UNIFORM) {
#pragma unroll
        for (int j = 0; j < 2; ++j) {
            const float* vp = Vacc + (size_t)(b0 + j * 8) * (OC * 16) + (oh * 5) * 16 + t4 * 4;
#pragma unroll
            for (int jo = 0; jo < 5; ++jo) {
                float4 v4 = *(const float4*)(vp + jo * 16);
                vac[j][jo][0] = asb(pk_rn(v4.x, v4.y));
                vac[j][jo][1] = asb(pk_rn(v4.z, v4.w));
            }
        }
    }

    float acc[2][5][4];
#pragma unroll
    for (int j = 0; j < 2; ++j)
#pragma unroll
        for (int jo = 0; jo < 5; ++jo)
#pragma unroll
            for (int k = 0; k < 4; ++k) acc[j][jo][k] = 0.f;

    for (int st = bid; st < NSTAGE; st += grid) {
        const int is = st * 16;
        __syncthreads();
        // stage W: 16*320 float4 -> f16 (5 iters/thread)
        for (int j = t; j < 16 * 320; j += 1024) {
            int iw = j / 320;
            int r  = j - iw * 320;
            int o  = r >> 5;
            int f  = r & 31;
            float4 w4 = *(const float4*)(W + (size_t)o * (IN * 128) +
                                         (size_t)(is + iw) * 128 + f * 4);
            *(uint2*)&Wl[iw * 1360 + o * 136 + f * 4] =
                make_uint2(pk_rn(w4.x, w4.y), pk_rn(w4.z, w4.w));
        }
        // stage x: 16*128 float4 -> f16
        for (int j = t; j < 16 * 128; j += 1024) {
            int bb = j >> 5;
            int r  = j & 31;
            int iw = r >> 1;
            int hh = r & 1;
            float4 x4 = *(const float4*)(x + (size_t)bb * (IN * 8) +
                                         (size_t)(is + iw) * 8 + hh * 4);
            *(uint2*)&xl[iw * 520 + bb * 8 + hh * 4] =
                make_uint2(pk_rn(x4.x, x4.y), pk_rn(x4.z, x4.w));
        }
        __syncthreads();

#pragma unroll 1
        for (int u = 0; u < 4; ++u) {
            const int il = ih * 4 + u;
            const unsigned short* wp = &Wl[il * 1360 + (oh * 5) * 136 + t4 * 32];
            const unsigned short* xp = &xl[il * 520];

            uint4 xq0 = *(const uint4*)(xp + b0 * 8);
            uint4 xq1 = *(const uint4*)(xp + (b0 + 8) * 8);
            h2 xv[2][4];
            xv[0][0] = asb(xq0.x); xv[0][1] = asb(xq0.y); xv[0][2] = asb(xq0.z); xv[0][3] = asb(xq0.w);
            xv[1][0] = asb(xq1.x); xv[1][1] = asb(xq1.y); xv[1][2] = asb(xq1.z); xv[1][3] = asb(xq1.w);

            float lg[2][5];
            h2 uh[2][5][2];
#pragma unroll
            for (int jo = 0; jo < 5; ++jo) {
                const unsigned short* wo = wp + jo * 136;
                uint4 q0 = *(const uint4*)(wo);
                uint4 q1 = *(const uint4*)(wo + 8);
                uint4 q2 = *(const uint4*)(wo + 16);
                uint4 q3 = *(const uint4*)(wo + 24);
#pragma unroll
                for (int j = 0; j < 2; ++j) {
                    float u0 = dot2(asb(q0.x), xv[j][0], 0.f);
                    u0 = dot2(asb(q0.y), xv[j][1], u0);
                    u0 = dot2(asb(q0.z), xv[j][2], u0);
                    u0 = dot2(asb(q0.w), xv[j][3], u0);
                    float u1 = dot2(asb(q1.x), xv[j][0], 0.f);
                    u1 = dot2(asb(q1.y), xv[j][1], u1);
                    u1 = dot2(asb(q1.z), xv[j][2], u1);
                    u1 = dot2(asb(q1.w), xv[j][3], u1);
                    float u2 = dot2(asb(q2.x), xv[j][0], 0.f);
                    u2 = dot2(asb(q2.y), xv[j][1], u2);
                    u2 = dot2(asb(q2.z), xv[j][2], u2);
                    u2 = dot2(asb(q2.w), xv[j][3], u2);
                    float u3 = dot2(asb(q3.x), xv[j][0], 0.f);
                    u3 = dot2(asb(q3.y), xv[j][1], u3);
                    u3 = dot2(asb(q3.z), xv[j][2], u3);
                    u3 = dot2(asb(q3.w), xv[j][3], u3);
                    if (UNIFORM) {   // c=0.1 folded into reduce scale
                        acc[j][jo][0] += u0;
                        acc[j][jo][1] += u1;
                        acc[j][jo][2] += u2;
                        acc[j][jo][3] += u3;
                    } else {
                        h2 pk0 = __builtin_amdgcn_cvt_pkrtz(u0, u1);
                        h2 pk1 = __builtin_amdgcn_cvt_pkrtz(u2, u3);
                        uh[j][jo][0] = pk0;
                        uh[j][jo][1] = pk1;
                        lg[j][jo] = dot2(pk0, vac[j][jo][0], dot2(pk1, vac[j][jo][1], 0.f));
                    }
                }
            }

            if (!UNIFORM) {
#pragma unroll
                for (int j = 0; j < 2; ++j) {
#pragma unroll
                    for (int jo = 0; jo < 5; ++jo) lg[j][jo] = quad_sum(lg[j][jo]);
                    float lo[5];
#pragma unroll
                    for (int jo = 0; jo < 5; ++jo) lo[jo] = __shfl_xor(lg[j][jo], 4);
                    float mx = lg[j][0];
#pragma unroll
                    for (int jo = 1; jo < 5; ++jo) mx = fmaxf(mx, lg[j][jo]);
#pragma unroll
                    for (int jo = 0; jo < 5; ++jo) mx = fmaxf(mx, lo[jo]);
                    float c[5];
                    float se = 0.f;
#pragma unroll
                    for (int jo = 0; jo < 5; ++jo) { c[jo] = __expf(lg[j][jo] - mx); se += c[jo]; }
#pragma unroll
                    for (int jo = 0; jo < 5; ++jo) se += __expf(lo[jo] - mx);
                    float rs = 1.f / se;
#pragma unroll
                    for (int jo = 0; jo < 5; ++jo) {
                        float cj = c[jo] * rs;
                        acc[j][jo][0] += cj * (float)uh[j][jo][0][0];
                        acc[j][jo][1] += cj * (float)uh[j][jo][0][1];
                        acc[j][jo][2] += cj * (float)uh[j][jo][1][0];
                        acc[j][jo][3] += cj * (float)uh[j][jo][1][1];
                    }
                }
            }
        }
    }

    // block reduce over ih-waves (red aliases Wl; R4 layout, 0 conflicts)
#pragma unroll 1
    for (int r = 0; r < 4; ++r) {
        __syncthreads();
        if (ih == r) {
#pragma unroll
            for (int j = 0; j < 2; ++j)
#pragma unroll
                for (int jo = 0; jo < 5; ++jo) {
                    float* p = &red[(size_t)(b0 + j * 8) * 160 + (oh * 5 + jo) * 16 + t4 * 4];
                    if (r == 0) {
                        *(float4*)p = make_float4(acc[j][jo][0], acc[j][jo][1],
                                                  acc[j][jo][2], acc[j][jo][3]);
                    } else {
                        float4 v = *(const float4*)p;
                        v.x += acc[j][jo][0]; v.y += acc[j][jo][1];
                        v.z += acc[j][jo][2]; v.w += acc[j][jo][3];
                        *(float4*)p = v;
                    }
                }
        }
    }
    __syncthreads();
    // flush partial as f16 (canonical [b][o][d]); 5120 uint stores
    unsigned int* dst = (unsigned int*)(part + (size_t)bid * PART_H);
    for (int q = t; q < PART_H / 2; q += 1024)
        dst[q] = pk_rn(red[2 * q], red[2 * q + 1]);
}

// Kernel B: one block per (b,o). Reduce f16 partials over chunks, scale,
// squash; write Vacc (mode 0 =, mode 1 +=) or final out (mode 2).
__global__ __launch_bounds__(256) void caps_reduce(
    const __fp16* __restrict__ part, float* __restrict__ Vacc,
    float* __restrict__ out, int nchunk, int mode, float scale)
{
    const int bo = blockIdx.x;      // b*10+o, [0,640)
    const int t  = threadIdx.x;
    const int d  = t & 15;
    const int s  = t >> 4;          // 16 slices over chunks

    const __fp16* base = part + (size_t)bo * 16 + d;
    float acc = 0.f;
    for (int c = s; c < nchunk; c += 16)
        acc += (float)base[(size_t)c * PART_H];

    __shared__ float red[16][17];
    red[s][d] = acc;
    __syncthreads();
    if (t < 16) {
        float sv = 0.f;
#pragma unroll
        for (int s2 = 0; s2 < 16; ++s2) sv += red[s2][t];
        sv *= scale;
        float n2 = sv * sv;
#pragma unroll
        for (int m = 1; m < 16; m <<= 1) n2 += __shfl_xor(n2, m);
        float norm = sqrtf(n2);
        float scl  = n2 / (1.f + n2) / (norm + 1e-8f);
        float v = scl * sv;
        if (mode == 2)      out[bo * 16 + t] = v;
        else if (mode == 0) Vacc[bo * 16 + t] = v;
        else                Vacc[bo * 16 + t] += v;
    }
}

extern "C" void kernel_launch(void* const* d_in, const int* in_sizes, int n_in,
                              void* d_out, int out_size, void* d_ws, size_t ws_size,
                              hipStream_t stream) {
    const float* x = (const float*)d_in[0];   // (64, 8000, 8)
    const float* W = (const float*)d_in[1];   // (10, 8000, 16, 8)
    float* out = (float*)d_out;               // (64, 10, 16)

    char* ws = (char*)d_ws;
    float*  Vacc = (float*)ws;                          // 40 KB fp32
    __fp16* part = (__fp16*)(ws + VACC_F * sizeof(float)); // grid x 20 KB f16

    size_t avail = (ws_size > VACC_F * sizeof(float)) ? ws_size - VACC_F * sizeof(float) : 0;
    long slots = (long)(avail / (PART_H * sizeof(__fp16)));
    int grid = (int)((slots < NSTAGE) ? slots : NSTAGE);
    if (grid < 1) grid = 1;

    // iter 0: uniform c (0.1 folded into reduce scale)
    caps_pass<1><<<grid, 1024, 0, stream>>>(W, x, Vacc, part);
    caps_reduce<<<640, 256, 0, stream>>>(part, Vacc, out, grid, 0, 0.1f);
    // iter 1
    caps_pass<0><<<grid, 1024, 0, stream>>>(W, x, Vacc, part);
    caps_reduce<<<640, 256, 0, stream>>>(part, Vacc, out, grid, 1, 1.0f);
    // iter 2 (final): write v to out
    caps_pass<0><<<grid, 1024, 0, stream>>>(W, x, Vacc, part);
    caps_reduce<<<640, 256, 0, stream>>>(part, Vacc, out, grid, 2, 1.0f);
}

// Round 9
// 209.500 us; speedup vs baseline: 3.7090x; 1.1545x over previous
//
#include <hip/hip_runtime.h>
#include <hip/hip_fp16.h>
#include <math.h>

#define IN 8000
#define OC 10
#define NSTAGE 500              // 500 stages x 16 i
#define VACC_F (64 * OC * 16)   // 10240 floats
#define PART_H (64 * OC * 16)   // 10240 halfs per block partial (20 KB)

typedef __fp16 h2 __attribute__((ext_vector_type(2)));

__device__ __forceinline__ h2 asb(unsigned int v) { return __builtin_bit_cast(h2, v); }

__device__ __forceinline__ float dot2(h2 a, h2 b, float c) {
#if __has_builtin(__builtin_amdgcn_fdot2)
    return __builtin_amdgcn_fdot2(a, b, c, false);
#else
    return fmaf((float)a[0], (float)b[0], fmaf((float)a[1], (float)b[1], c));
#endif
}

__device__ __forceinline__ unsigned int pk_rn(float a, float b) {
    return __builtin_bit_cast(unsigned int, __float22half2_rn(make_float2(a, b)));
}

// t4-quad sum (lanes xor1, xor2) on the VALU via DPP quad_perm
__device__ __forceinline__ float quad_sum(float v) {
    int a = __builtin_bit_cast(int, v);
    int s1 = __builtin_amdgcn_update_dpp(0, a, 0xB1, 0xF, 0xF, true);  // [1,0,3,2]
    float v1 = v + __builtin_bit_cast(float, s1);
    int a2 = __builtin_bit_cast(int, v1);
    int s2 = __builtin_amdgcn_update_dpp(0, a2, 0x4E, 0xF, 0xF, true); // [2,3,0,1]
    return v1 + __builtin_bit_cast(float, s2);
}

// Kernel A: 512-thr blocks (8 waves = 4 bh x 2 ih), grid up to 500.
// __launch_bounds__(512,4): VGPR cap 128 — enough for the routing pass's
// ~124 live values (R8's 1024-thr/64-VGPR build rematerialized LDS reads),
// while 2 blocks/CU (16 waves, 2x60416 B LDS) gives independent barrier
// domains so one block's staging overlaps the other's compute.
// Lane = (bl:3 | oh:1 | t4:2). Thread owns b in {bh*16+bl, +8},
// o in [5*oh,5*oh+5), d in [4*t4,4*t4+4); i-slots il = ih*8+u, u 0..7.
template<int UNIFORM>
__global__ __launch_bounds__(512, 4) void caps_pass(
    const float* __restrict__ W, const float* __restrict__ x,
    const float* __restrict__ Vacc, __fp16* __restrict__ part)
{
    __shared__ __align__(16) unsigned short Wl[16 * OC * 136];  // 43520 B
    __shared__ __align__(16) unsigned short xl[16 * 520];       // 16640 B
    float* red = (float*)Wl;                                    // 10240 f alias

    const int t    = threadIdx.x;
    const int w    = t >> 6;
    const int bh   = w >> 1;           // 0..3
    const int ih   = w & 1;            // 0..1
    const int lane = t & 63;
    const int bl   = lane >> 3;
    const int oh   = (lane >> 2) & 1;
    const int t4   = lane & 3;
    const int b0   = bh * 16 + bl;     // second batch: b0 + 8
    const int bid  = blockIdx.x;
    const int grid = gridDim.x;

    h2 vac[2][5][2];
    if (!UNIFORM) {
#pragma unroll
        for (int j = 0; j < 2; ++j) {
            const float* vp = Vacc + (size_t)(b0 + j * 8) * (OC * 16) + (oh * 5) * 16 + t4 * 4;
#pragma unroll
            for (int jo = 0; jo < 5; ++jo) {
                float4 v4 = *(const float4*)(vp + jo * 16);
                vac[j][jo][0] = asb(pk_rn(v4.x, v4.y));
                vac[j][jo][1] = asb(pk_rn(v4.z, v4.w));
            }
        }
    }

    float acc[2][5][4];
#pragma unroll
    for (int j = 0; j < 2; ++j)
#pragma unroll
        for (int jo = 0; jo < 5; ++jo)
#pragma unroll
            for (int k = 0; k < 4; ++k) acc[j][jo][k] = 0.f;

    for (int st = bid; st < NSTAGE; st += grid) {
        const int is = st * 16;
        __syncthreads();
        // stage W: 16*320 float4 -> f16 (10 iters/thread)
        for (int j = t; j < 16 * 320; j += 512) {
            int iw = j / 320;
            int r  = j - iw * 320;
            int o  = r >> 5;
            int f  = r & 31;
            float4 w4 = *(const float4*)(W + (size_t)o * (IN * 128) +
                                         (size_t)(is + iw) * 128 + f * 4);
            *(uint2*)&Wl[iw * 1360 + o * 136 + f * 4] =
                make_uint2(pk_rn(w4.x, w4.y), pk_rn(w4.z, w4.w));
        }
        // stage x: 16*128 float4 -> f16 (4 iters/thread)
        for (int j = t; j < 16 * 128; j += 512) {
            int bb = j >> 5;
            int r  = j & 31;
            int iw = r >> 1;
            int hh = r & 1;
            float4 x4 = *(const float4*)(x + (size_t)bb * (IN * 8) +
                                         (size_t)(is + iw) * 8 + hh * 4);
            *(uint2*)&xl[iw * 520 + bb * 8 + hh * 4] =
                make_uint2(pk_rn(x4.x, x4.y), pk_rn(x4.z, x4.w));
        }
        __syncthreads();

#pragma unroll 1
        for (int u = 0; u < 8; ++u) {
            const int il = ih * 8 + u;
            const unsigned short* wp = &Wl[il * 1360 + (oh * 5) * 136 + t4 * 32];
            const unsigned short* xp = &xl[il * 520];

            uint4 xq0 = *(const uint4*)(xp + b0 * 8);
            uint4 xq1 = *(const uint4*)(xp + (b0 + 8) * 8);
            h2 xv[2][4];
            xv[0][0] = asb(xq0.x); xv[0][1] = asb(xq0.y); xv[0][2] = asb(xq0.z); xv[0][3] = asb(xq0.w);
            xv[1][0] = asb(xq1.x); xv[1][1] = asb(xq1.y); xv[1][2] = asb(xq1.z); xv[1][3] = asb(xq1.w);

            float lg[2][5];
            h2 uh[2][5][2];
#pragma unroll
            for (int jo = 0; jo < 5; ++jo) {
                const unsigned short* wo = wp + jo * 136;
                uint4 q0 = *(const uint4*)(wo);
                uint4 q1 = *(const uint4*)(wo + 8);
                uint4 q2 = *(const uint4*)(wo + 16);
                uint4 q3 = *(const uint4*)(wo + 24);
#pragma unroll
                for (int j = 0; j < 2; ++j) {
                    float u0 = dot2(asb(q0.x), xv[j][0], 0.f);
                    u0 = dot2(asb(q0.y), xv[j][1], u0);
                    u0 = dot2(asb(q0.z), xv[j][2], u0);
                    u0 = dot2(asb(q0.w), xv[j][3], u0);
                    float u1 = dot2(asb(q1.x), xv[j][0], 0.f);
                    u1 = dot2(asb(q1.y), xv[j][1], u1);
                    u1 = dot2(asb(q1.z), xv[j][2], u1);
                    u1 = dot2(asb(q1.w), xv[j][3], u1);
                    float u2 = dot2(asb(q2.x), xv[j][0], 0.f);
                    u2 = dot2(asb(q2.y), xv[j][1], u2);
                    u2 = dot2(asb(q2.z), xv[j][2], u2);
                    u2 = dot2(asb(q2.w), xv[j][3], u2);
                    float u3 = dot2(asb(q3.x), xv[j][0], 0.f);
                    u3 = dot2(asb(q3.y), xv[j][1], u3);
                    u3 = dot2(asb(q3.z), xv[j][2], u3);
                    u3 = dot2(asb(q3.w), xv[j][3], u3);
                    if (UNIFORM) {   // c=0.1 folded into reduce scale
                        acc[j][jo][0] += u0;
                        acc[j][jo][1] += u1;
                        acc[j][jo][2] += u2;
                        acc[j][jo][3] += u3;
                    } else {
                        h2 pk0 = __builtin_amdgcn_cvt_pkrtz(u0, u1);
                        h2 pk1 = __builtin_amdgcn_cvt_pkrtz(u2, u3);
                        uh[j][jo][0] = pk0;
                        uh[j][jo][1] = pk1;
                        lg[j][jo] = dot2(pk0, vac[j][jo][0], dot2(pk1, vac[j][jo][1], 0.f));
                    }
                }
            }

            if (!UNIFORM) {
#pragma unroll
                for (int j = 0; j < 2; ++j) {
#pragma unroll
                    for (int jo = 0; jo < 5; ++jo) lg[j][jo] = quad_sum(lg[j][jo]);
                    float lo[5];
#pragma unroll
                    for (int jo = 0; jo < 5; ++jo) lo[jo] = __shfl_xor(lg[j][jo], 4);
                    float mx = lg[j][0];
#pragma unroll
                    for (int jo = 1; jo < 5; ++jo) mx = fmaxf(mx, lg[j][jo]);
#pragma unroll
                    for (int jo = 0; jo < 5; ++jo) mx = fmaxf(mx, lo[jo]);
                    float c[5];
                    float se = 0.f;
#pragma unroll
                    for (int jo = 0; jo < 5; ++jo) { c[jo] = __expf(lg[j][jo] - mx); se += c[jo]; }
#pragma unroll
                    for (int jo = 0; jo < 5; ++jo) se += __expf(lo[jo] - mx);
                    float rs = 1.f / se;
#pragma unroll
                    for (int jo = 0; jo < 5; ++jo) {
                        float cj = c[jo] * rs;
                        acc[j][jo][0] += cj * (float)uh[j][jo][0][0];
                        acc[j][jo][1] += cj * (float)uh[j][jo][0][1];
                        acc[j][jo][2] += cj * (float)uh[j][jo][1][0];
                        acc[j][jo][3] += cj * (float)uh[j][jo][1][1];
                    }
                }
            }
        }
    }

    // block reduce over the 2 ih-waves per bh (red aliases Wl; proven layout)
#pragma unroll 1
    for (int r = 0; r < 2; ++r) {
        __syncthreads();
        if (ih == r) {
#pragma unroll
            for (int j = 0; j < 2; ++j)
#pragma unroll
                for (int jo = 0; jo < 5; ++jo) {
                    float* p = &red[(size_t)(b0 + j * 8) * 160 + (oh * 5 + jo) * 16 + t4 * 4];
                    if (r == 0) {
                        *(float4*)p = make_float4(acc[j][jo][0], acc[j][jo][1],
                                                  acc[j][jo][2], acc[j][jo][3]);
                    } else {
                        float4 v = *(const float4*)p;
                        v.x += acc[j][jo][0]; v.y += acc[j][jo][1];
                        v.z += acc[j][jo][2]; v.w += acc[j][jo][3];
                        *(float4*)p = v;
                    }
                }
        }
    }
    __syncthreads();
    // flush partial as f16 (canonical [b][o][d])
    unsigned int* dst = (unsigned int*)(part + (size_t)bid * PART_H);
    for (int q = t; q < PART_H / 2; q += 512)
        dst[q] = pk_rn(red[2 * q], red[2 * q + 1]);
}

// Kernel B: one block per (b,o). uint2 loads (4 halfs), 64 chunk-slices ->
// 8 independent loads/thread; wave shuffle tree + tiny LDS; squash.
// mode 0: Vacc =, mode 1: Vacc +=, mode 2: out =.
__global__ __launch_bounds__(256) void caps_reduce(
    const __fp16* __restrict__ part, float* __restrict__ Vacc,
    float* __restrict__ out, int nchunk, int mode, float scale)
{
    const int bo = blockIdx.x;      // b*10+o, [0,640)
    const int t  = threadIdx.x;
    const int d2 = t & 3;           // 4 d's: 4*d2..4*d2+3
    const int s  = t >> 2;          // 64 chunk slices

    float4 a = make_float4(0.f, 0.f, 0.f, 0.f);
    for (int c = s; c < nchunk; c += 64) {
        uint2 v = *(const uint2*)(part + (size_t)c * PART_H + bo * 16 + d2 * 4);
        h2 lo = asb(v.x), hi = asb(v.y);
        a.x += (float)lo[0]; a.y += (float)lo[1];
        a.z += (float)hi[0]; a.w += (float)hi[1];
    }
    // reduce over s within the wave: s-bits are t bits 2..5 -> xor 4,8,16,32
#pragma unroll
    for (int m = 4; m <= 32; m <<= 1) {
        a.x += __shfl_xor(a.x, m); a.y += __shfl_xor(a.y, m);
        a.z += __shfl_xor(a.z, m); a.w += __shfl_xor(a.w, m);
    }
    __shared__ float red[4][16];
    const int wv = t >> 6;
    if ((t & 63) < 4) {
        red[wv][d2 * 4 + 0] = a.x; red[wv][d2 * 4 + 1] = a.y;
        red[wv][d2 * 4 + 2] = a.z; red[wv][d2 * 4 + 3] = a.w;
    }
    __syncthreads();
    if (t < 16) {
        float sv = (red[0][t] + red[1][t] + red[2][t] + red[3][t]) * scale;
        float n2 = sv * sv;
#pragma unroll
        for (int m = 1; m < 16; m <<= 1) n2 += __shfl_xor(n2, m);
        float norm = sqrtf(n2);
        float scl  = n2 / (1.f + n2) / (norm + 1e-8f);
        float v = scl * sv;
        if (mode == 2)      out[bo * 16 + t] = v;
        else if (mode == 0) Vacc[bo * 16 + t] = v;
        else                Vacc[bo * 16 + t] += v;
    }
}

extern "C" void kernel_launch(void* const* d_in, const int* in_sizes, int n_in,
                              void* d_out, int out_size, void* d_ws, size_t ws_size,
                              hipStream_t stream) {
    const float* x = (const float*)d_in[0];   // (64, 8000, 8)
    const float* W = (const float*)d_in[1];   // (10, 8000, 16, 8)
    float* out = (float*)d_out;               // (64, 10, 16)

    char* ws = (char*)d_ws;
    float*  Vacc = (float*)ws;                             // 40 KB fp32
    __fp16* part = (__fp16*)(ws + VACC_F * sizeof(float)); // grid x 20 KB f16

    size_t avail = (ws_size > VACC_F * sizeof(float)) ? ws_size - VACC_F * sizeof(float) : 0;
    long slots = (long)(avail / (PART_H * sizeof(__fp16)));
    int grid = (int)((slots < NSTAGE) ? slots : NSTAGE);
    if (grid < 1) grid = 1;

    // iter 0: uniform c (0.1 folded into reduce scale)
    caps_pass<1><<<grid, 512, 0, stream>>>(W, x, Vacc, part);
    caps_reduce<<<640, 256, 0, stream>>>(part, Vacc, out, grid, 0, 0.1f);
    // iter 1
    caps_pass<0><<<grid, 512, 0, stream>>>(W, x, Vacc, part);
    caps_reduce<<<640, 256, 0, stream>>>(part, Vacc, out, grid, 1, 1.0f);
    // iter 2 (final): write v to out
    caps_pass<0><<<grid, 512, 0, stream>>>(W, x, Vacc, part);
    caps_reduce<<<640, 256, 0, stream>>>(part, Vacc, out, grid, 2, 1.0f);
}